// Round 5
// baseline (402.897 us; speedup 1.0000x reference)
//
#include <hip/hip_runtime.h>
#include <hip/hip_bf16.h>

typedef short bf16x8 __attribute__((ext_vector_type(8)));
typedef float f32x4 __attribute__((ext_vector_type(4)));
typedef unsigned short u16;

#define LOG2E 1.44269504088896340736f

__device__ __forceinline__ u16 f2bf(float f) {
    unsigned u = __float_as_uint(f);
    u += 0x7fffu + ((u >> 16) & 1u);   // round-to-nearest-even
    return (u16)(u >> 16);
}
__device__ __forceinline__ float bf2f(u16 h) {
    return __uint_as_float(((unsigned)h) << 16);
}

// ---------------------------------------------------------------------------
// Kernel 0: weight prep. Combined rows: [0,256)=Wv, [256,288)=Wq*log2e, [288,320)=Wk.
// Split each f32 weight into bf16 hi + bf16 lo. Combined bias (q-bias pre-scaled).
// ---------------------------------------------------------------------------
__global__ void k_prep(const float* __restrict__ Wq, const float* __restrict__ bq,
                       const float* __restrict__ Wk, const float* __restrict__ bk,
                       const float* __restrict__ Wv, const float* __restrict__ bv,
                       u16* __restrict__ Whi, u16* __restrict__ Wlo,
                       float* __restrict__ bias) {
    int idx = blockIdx.x * 256 + threadIdx.x;
    if (idx >= 320 * 256) return;
    int row = idx >> 8, c = idx & 255;
    float w, b;
    if (row < 256)      { w = Wv[row * 256 + c];                  b = bv[row]; }
    else if (row < 288) { w = Wq[(row - 256) * 256 + c] * LOG2E;  b = bq[row - 256] * LOG2E; }
    else                { w = Wk[(row - 288) * 256 + c];          b = bk[row - 288]; }
    u16 hi = f2bf(w);
    Whi[idx] = hi;
    Wlo[idx] = f2bf(w - bf2f(hi));
    if (c == 0) bias[row] = b;
}

// ---------------------------------------------------------------------------
// Kernel 1: fused QKV projection. out[320 rows][4096 n] per batch via MFMA.
// 3-term split product: Whi*xhi + Whi*xlo + Wlo*xhi  (~fp32 accuracy).
// Writes: vbf[b][256][4096] bf16 ; qt/kt[b][4096][64] bf16 (cols 0..31 hi, 32..63 lo)
// ---------------------------------------------------------------------------
#define XPAD 264  // xT row stride in elems (=528B, 16B-multiple, conflict-friendly)

__global__ __launch_bounds__(256) void k_proj(
    const float* __restrict__ x, const u16* __restrict__ Whi,
    const u16* __restrict__ Wlo, const float* __restrict__ bias,
    u16* __restrict__ qt, u16* __restrict__ kt, u16* __restrict__ vbf) {
    __shared__ __attribute__((aligned(16))) u16 xh[64 * XPAD];
    __shared__ __attribute__((aligned(16))) u16 xl[64 * XPAD];
    int bid = blockIdx.x;
    int b = bid & 7, nt = bid >> 3;
    int n0 = nt * 64;
    int t = threadIdx.x;
    int lane = t & 63, w = t >> 6;
    int lr = lane & 15, lk = lane >> 4;

    // ---- stage x tile transposed + bf16-split into LDS ----
    {
        int n = t & 63;
        int cg = t >> 6;
        for (int it = 0; it < 8; ++it) {
            int c8 = (it * 4 + cg) * 8;
            bf16x8 hv, lv;
#pragma unroll
            for (int u = 0; u < 8; ++u) {
                float xv = x[((size_t)(b * 256 + c8 + u)) * 4096 + n0 + n];
                u16 hu = f2bf(xv);
                hv[u] = (short)hu;
                lv[u] = (short)f2bf(xv - bf2f(hu));
            }
            *(bf16x8*)&xh[n * XPAD + c8] = hv;
            *(bf16x8*)&xl[n * XPAD + c8] = lv;
        }
    }
    __syncthreads();

    f32x4 acc[5][4];
#pragma unroll
    for (int i = 0; i < 5; i++)
#pragma unroll
        for (int j = 0; j < 4; j++) acc[i][j] = (f32x4){0.f, 0.f, 0.f, 0.f};

    for (int cs = 0; cs < 8; ++cs) {
        int c0 = cs * 32;
        bf16x8 ah[5], al[5], bh[4], bl[4];
#pragma unroll
        for (int mt = 0; mt < 5; ++mt) {
            int row = (w * 5 + mt) * 16 + lr;
            ah[mt] = *(const bf16x8*)&Whi[row * 256 + c0 + lk * 8];
            al[mt] = *(const bf16x8*)&Wlo[row * 256 + c0 + lk * 8];
        }
#pragma unroll
        for (int ns = 0; ns < 4; ++ns) {
            int np = ns * 16 + lr;
            bh[ns] = *(const bf16x8*)&xh[np * XPAD + c0 + lk * 8];
            bl[ns] = *(const bf16x8*)&xl[np * XPAD + c0 + lk * 8];
        }
#pragma unroll
        for (int mt = 0; mt < 5; ++mt)
#pragma unroll
            for (int ns = 0; ns < 4; ++ns) {
                acc[mt][ns] = __builtin_amdgcn_mfma_f32_16x16x32_bf16(ah[mt], bh[ns], acc[mt][ns], 0, 0, 0);
                acc[mt][ns] = __builtin_amdgcn_mfma_f32_16x16x32_bf16(ah[mt], bl[ns], acc[mt][ns], 0, 0, 0);
                acc[mt][ns] = __builtin_amdgcn_mfma_f32_16x16x32_bf16(al[mt], bh[ns], acc[mt][ns], 0, 0, 0);
            }
    }

    // ---- epilogue: bias + scatter to v / q(hi,lo) / k(hi,lo) ----
#pragma unroll
    for (int mt = 0; mt < 5; ++mt) {
        int tile = w * 5 + mt;  // 0..19 ; 16-row tiles never straddle v/q/k regions
#pragma unroll
        for (int ns = 0; ns < 4; ++ns) {
#pragma unroll
            for (int r = 0; r < 4; ++r) {
                int row = tile * 16 + lk * 4 + r;
                int n = n0 + ns * 16 + lr;
                float val = acc[mt][ns][r] + bias[row];
                if (row < 256) {
                    vbf[((size_t)(b * 256 + row)) * 4096 + n] = f2bf(val);
                } else if (row < 288) {
                    u16 hi = f2bf(val);
                    size_t base = ((size_t)(b * 4096 + n)) * 64 + (row - 256);
                    qt[base] = hi;
                    qt[base + 32] = f2bf(val - bf2f(hi));
                } else {
                    u16 hi = f2bf(val);
                    size_t base = ((size_t)(b * 4096 + n)) * 64 + (row - 288);
                    kt[base] = hi;
                    kt[base + 32] = f2bf(val - bf2f(hi));
                }
            }
        }
    }
}

// ---------------------------------------------------------------------------
// Kernel 2: flash attention (softmax over i), PRODUCER-CONSUMER design.
// 512 threads = 8 waves. Waves 0-3 (producers): QK^T + online softmax + P/sc
// publish for j-subtile w (16 cols), running ONE ITERATION AHEAD. Waves 4-7
// (consumers): rescale + PV for c-chunk (w-4)*64 over all 64 j. P/sc double-
// buffered; ONE block-convergent barrier per 64-i tile. Producer VALU chain
// overlaps consumer MFMA on the same SIMD (separate pipes). Output f32.
// ---------------------------------------------------------------------------
#define PSTR 72  // P row stride in u16: 64 i + pad; 144B rows (16B-aligned)

__global__ __launch_bounds__(512, 4) void k_attn(
    const u16* __restrict__ qt, const u16* __restrict__ kt,
    const u16* __restrict__ vbf, const float* __restrict__ x,
    const float* __restrict__ gamma, float* __restrict__ out) {
    __shared__ __attribute__((aligned(16))) u16 P[2][4][16][PSTR];  // 18.4 KB
    __shared__ float sc[2][64];
    __shared__ float lbuf[64];
    int bid = blockIdx.x;
    int b = bid & 7, jt = bid >> 3;  // b = bid%8 pins batch -> XCD (L2 locality)
    int t = threadIdx.x;
    int lane = t & 63, w = t >> 6;   // w in 0..7
    int lr = lane & 15, lk = lane >> 4;
    int j0 = jt * 64;
    int wp = w & 3;                  // producer j-subtile / consumer c-chunk idx
    bool is_prod = (w < 4);

    // K fragments (producers use; consumers load same addrs -> L1 hit, discarded)
    size_t kb = ((size_t)(b * 4096 + j0 + wp * 16 + lr)) * 64 + lk * 8;
    bf16x8 khi = *(const bf16x8*)&kt[kb];
    bf16x8 klo = *(const bf16x8*)&kt[kb + 32];

    float mcur = -3.0e38f, lsum = 0.f;       // producer softmax state
    f32x4 acc[4][4];                          // consumer accumulator
#pragma unroll
    for (int i = 0; i < 4; i++)
#pragma unroll
        for (int j = 0; j < 4; j++) acc[i][j] = (f32x4){0.f, 0.f, 0.f, 0.f};
    const f32x4 zero = {0.f, 0.f, 0.f, 0.f};

    // ---- producer step: QK^T + softmax for i-tile `it`, publish P[it&1] ----
    auto prod_step = [&](int it) {
        int i0 = it * 64, p = it & 1;
        bf16x8 qh[4], ql[4];
#pragma unroll
        for (int g = 0; g < 4; ++g) {
            size_t qb = ((size_t)(b * 4096 + i0 + g * 16 + lr)) * 64 + lk * 8;
            qh[g] = *(const bf16x8*)&qt[qb];
            ql[g] = *(const bf16x8*)&qt[qb + 32];
        }
        f32x4 s[4];
#pragma unroll
        for (int g = 0; g < 4; ++g) {
            s[g] = __builtin_amdgcn_mfma_f32_16x16x32_bf16(qh[g], khi, zero, 0, 0, 0);
            s[g] = __builtin_amdgcn_mfma_f32_16x16x32_bf16(qh[g], klo, s[g], 0, 0, 0);
            s[g] = __builtin_amdgcn_mfma_f32_16x16x32_bf16(ql[g], khi, s[g], 0, 0, 0);
        }
        float tm = -3.0e38f;
#pragma unroll
        for (int g = 0; g < 4; ++g)
            tm = fmaxf(tm, fmaxf(fmaxf(s[g][0], s[g][1]), fmaxf(s[g][2], s[g][3])));
        tm = fmaxf(tm, __shfl_xor(tm, 16));
        tm = fmaxf(tm, __shfl_xor(tm, 32));
        float mnew = fmaxf(mcur, tm);
        float scale = exp2f(mcur - mnew);   // == 1.0f exactly when no growth
        mcur = mnew;
        lsum *= scale;
#pragma unroll
        for (int g = 0; g < 4; ++g) {
            float p0 = exp2f(s[g][0] - mcur), p1 = exp2f(s[g][1] - mcur);
            float p2 = exp2f(s[g][2] - mcur), p3 = exp2f(s[g][3] - mcur);
            lsum += (p0 + p1) + (p2 + p3);
            uint2 pk;
            pk.x = ((unsigned)f2bf(p1) << 16) | f2bf(p0);
            pk.y = ((unsigned)f2bf(p3) << 16) | f2bf(p2);
            *(uint2*)&P[p][wp][lr][g * 16 + lk * 4] = pk;
        }
        if (lk == 0) sc[p][wp * 16 + lr] = scale;
    };

    // ---- consumer step: rescale + PV with P[it&1] ----
    auto cons_step = [&](int it) {
        int i0 = it * 64, p = it & 1;
        bf16x8 av0[4];
#pragma unroll
        for (int ct = 0; ct < 4; ++ct)   // issue i-half 0 loads early
            av0[ct] = *(const bf16x8*)&vbf[((size_t)(b * 256 + wp * 64 + ct * 16 + lr)) * 4096
                                           + i0 + lk * 8];
        float rs[4];
#pragma unroll
        for (int js = 0; js < 4; ++js) rs[js] = sc[p][js * 16 + lr];
        if (__any((rs[0] != 1.f) | (rs[1] != 1.f) | (rs[2] != 1.f) | (rs[3] != 1.f))) {
#pragma unroll
            for (int ct = 0; ct < 4; ++ct)
#pragma unroll
                for (int js = 0; js < 4; ++js)
#pragma unroll
                    for (int r = 0; r < 4; ++r) acc[ct][js][r] *= rs[js];
        }
        bf16x8 av1[4];
#pragma unroll
        for (int ct = 0; ct < 4; ++ct)   // issue i-half 1 while half-0 MFMAs run
            av1[ct] = *(const bf16x8*)&vbf[((size_t)(b * 256 + wp * 64 + ct * 16 + lr)) * 4096
                                           + i0 + 32 + lk * 8];
        {
            bf16x8 bp[4];
#pragma unroll
            for (int js = 0; js < 4; ++js)
                bp[js] = *(const bf16x8*)&P[p][js][lr][lk * 8];
#pragma unroll
            for (int ct = 0; ct < 4; ++ct)
#pragma unroll
                for (int js = 0; js < 4; ++js)
                    acc[ct][js] = __builtin_amdgcn_mfma_f32_16x16x32_bf16(av0[ct], bp[js], acc[ct][js], 0, 0, 0);
        }
        {
            bf16x8 bp[4];
#pragma unroll
            for (int js = 0; js < 4; ++js)
                bp[js] = *(const bf16x8*)&P[p][js][lr][32 + lk * 8];
#pragma unroll
            for (int ct = 0; ct < 4; ++ct)
#pragma unroll
                for (int js = 0; js < 4; ++js)
                    acc[ct][js] = __builtin_amdgcn_mfma_f32_16x16x32_bf16(av1[ct], bp[js], acc[ct][js], 0, 0, 0);
        }
    };

    // ---- pipeline: producers run one i-tile ahead ----
    if (is_prod) prod_step(0);
    for (int tt = 0; tt < 64; ++tt) {
        __syncthreads();                 // publishes P/sc[tt&1]; block-convergent
        if (is_prod) {
            if (tt < 63) prod_step(tt + 1);
        } else {
            cons_step(tt);
        }
    }

    // ---- epilogue: producers hand over l; consumers write output ----
    if (is_prod) {
        lsum += __shfl_xor(lsum, 16);
        lsum += __shfl_xor(lsum, 32);
        if (lk == 0) lbuf[wp * 16 + lr] = lsum;
    }
    __syncthreads();
    if (!is_prod) {
        float g = gamma[0];
        float linv[4];
#pragma unroll
        for (int js = 0; js < 4; ++js) linv[js] = g / lbuf[js * 16 + lr];
#pragma unroll
        for (int ct = 0; ct < 4; ++ct)
#pragma unroll
            for (int r = 0; r < 4; ++r) {
                int c = wp * 64 + ct * 16 + lk * 4 + r;
                size_t base = ((size_t)(b * 256 + c)) * 4096 + j0;
#pragma unroll
                for (int js = 0; js < 4; ++js) {
                    int j = js * 16 + lr;
                    out[base + j] = acc[ct][js][r] * linv[js] + x[base + j];
                }
            }
    }
}

// ---------------------------------------------------------------------------
extern "C" void kernel_launch(void* const* d_in, const int* in_sizes, int n_in,
                              void* d_out, int out_size, void* d_ws, size_t ws_size,
                              hipStream_t stream) {
    const float* x = (const float*)d_in[0];
    const float* Wq = (const float*)d_in[1];
    const float* bq = (const float*)d_in[2];
    const float* Wk = (const float*)d_in[3];
    const float* bk = (const float*)d_in[4];
    const float* Wv = (const float*)d_in[5];
    const float* bv = (const float*)d_in[6];
    const float* gamma = (const float*)d_in[7];

    char* ws = (char*)d_ws;
    u16* Whi = (u16*)ws;                               // 163840 B
    u16* Wlo = (u16*)(ws + 163840);                    // 163840 B
    float* bias = (float*)(ws + 327680);               // 1280 B
    u16* qt = (u16*)(ws + 329216);                     // 4 MB  [8][4096][64]
    u16* kt = (u16*)(ws + 329216 + 4194304);           // 4 MB
    u16* vbf = (u16*)(ws + 329216 + 8388608);          // 16 MB [8][256][4096]
    // total ws use ~25.5 MB

    k_prep<<<320, 256, 0, stream>>>(Wq, bq, Wk, bk, Wv, bv, Whi, Wlo, bias);
    k_proj<<<512, 256, 0, stream>>>(x, Whi, Wlo, bias, qt, kt, vbf);
    k_attn<<<512, 512, 0, stream>>>(qt, kt, vbf, x, gamma, (float*)d_out);
}